// Round 11
// baseline (190.160 us; speedup 1.0000x reference)
//
#include <hip/hip_runtime.h>

// Problem constants (from reference)
#define N_NODES 2048
#define C_CH    128
#define NIRR    9
#define E_EL    10
// dslot mapping: 0 -> l0 (d=0), 1..3 -> l1 (d=0..2)

#define NS3 165
#define NS2 45

// Compile-time index tables for the flattened symmetric triple loop
// (used with compile-time indices only -> folds to immediates).
struct Tab {
    unsigned char pairP[NS2], pairQ[NS2];
    unsigned char triPair[NS3], triI[NS3];
};
constexpr Tab makeTab() {
    Tab t{};
    int s2 = 0, s3 = 0;
    for (int p = 0; p < 9; p++)
        for (int q = p; q < 9; q++) {
            t.pairP[s2] = (unsigned char)p;
            t.pairQ[s2] = (unsigned char)q;
            for (int i = q; i < 9; i++) {
                t.triPair[s3] = (unsigned char)s2;
                t.triI[s3] = (unsigned char)i;
                s3++;
            }
            s2++;
        }
    return t;
}
constexpr Tab TAB = makeTab();

// Single fused kernel: per-block table symmetrization (LDS) + contraction +
// o3.Linear + skip. One node per block; block = 512 = 128 c x 4 roles
// (role r = dslot r). Eliminates the build_sym launch entirely (the ~80 us
// total-minus-kernel gap scales with launch count).
// Table reads are wave-uniform ds_read_b128 broadcasts (same-address across
// lanes = conflict-free per G4).
// NOTE: VGPR cap must stay >=128: (512,4) -> 128. R5's 64-cap spilled (14x).
__global__ __launch_bounds__(512, 4) void fused_kernel(
    const float* __restrict__ x, const float* __restrict__ y,
    const float* __restrict__ u3_l0, const float* __restrict__ u2_l0, const float* __restrict__ u1_l0,
    const float* __restrict__ u3_l1, const float* __restrict__ u2_l1, const float* __restrict__ u1_l1,
    const float* __restrict__ w3_l0, const float* __restrict__ w2_l0, const float* __restrict__ w1_l0,
    const float* __restrict__ w3_l1, const float* __restrict__ w2_l1, const float* __restrict__ w1_l1,
    const float* __restrict__ lw0, const float* __restrict__ lw1,
    const float* __restrict__ sc, float* __restrict__ out)
{
    __shared__ float lus3[4 * NS3 * 4];   // [r][s][k4]      10560 B
    __shared__ float lus2[4 * NS2 * 4];   // [r][s][k3 pad4]  2880 B
    __shared__ float lus1[4 * 9 * 2];     // [r][p][k2]        288 B
    __shared__ float fs[4][132];          // [dslot][c]       2112 B

    int tid = threadIdx.x;

    // ---- Phase 1: cooperative table symmetrization into LDS ----
    // us3: 2640 entries, 6-perm fold each
    for (int t = tid; t < 4 * NS3 * 4; t += 512) {
        int k = t & 3;
        int rs = t >> 2;
        int s = rs % NS3;
        int ds = rs / NS3;
        // decode s -> (pp<=qq<=ii) by scan (cheap int ops)
        int pp = 0, qq = 0, ii = 0, cntr = 0;
        for (int p = 0; p < 9; p++)
            for (int q = p; q < 9; q++)
                for (int i = q; i < 9; i++) {
                    if (cntr == s) { pp = p; qq = q; ii = i; }
                    cntr++;
                }
        const float* u = (ds == 0) ? u3_l0 : (u3_l1 + (ds - 1) * 2916);
        int perm[6][3] = {{pp,qq,ii},{pp,ii,qq},{qq,pp,ii},{qq,ii,pp},{ii,pp,qq},{ii,qq,pp}};
        float acc = 0.f;
        #pragma unroll
        for (int j = 0; j < 6; j++)
            acc += u[((perm[j][0] * 9 + perm[j][1]) * 9 + perm[j][2]) * 4 + k];
        float mult = (pp == qq && qq == ii) ? 6.f : ((pp == qq || qq == ii) ? 2.f : 1.f);
        lus3[t] = acc / mult;
    }
    // us2: 720 padded entries (k=3 slot zeroed)
    for (int t = tid; t < 4 * NS2 * 4; t += 512) {
        int k = t & 3;
        int rs = t >> 2;
        int s = rs % NS2;
        int ds = rs / NS2;
        float v = 0.f;
        if (k < 3) {
            int pp = 0, qq = 0, cntr = 0;
            for (int p = 0; p < 9; p++)
                for (int q = p; q < 9; q++) {
                    if (cntr == s) { pp = p; qq = q; }
                    cntr++;
                }
            const float* u = (ds == 0) ? u2_l0 : (u2_l1 + (ds - 1) * 243);
            float acc = u[(pp * 9 + qq) * 3 + k] + u[(qq * 9 + pp) * 3 + k];
            v = (pp == qq) ? acc * 0.5f : acc;
        }
        lus2[t] = v;
    }
    // us1: 72 entries (identity copy)
    if (tid < 72) {
        int k = tid & 1;
        int rp = tid >> 1;
        int p = rp % 9;
        int ds = rp / 9;
        const float* u = (ds == 0) ? u1_l0 : (u1_l1 + (ds - 1) * 18);
        lus1[tid] = u[p * 2 + k];
    }

    int c = tid & 127;
    int r = __builtin_amdgcn_readfirstlane(tid >> 7);   // role == dslot, wave-uniform
    int b = blockIdx.x;

    int e = 0;
    #pragma unroll
    for (int k = 1; k < E_EL; k++)
        if (y[b * E_EL + k] > 0.5f) e = k;
    e = __builtin_amdgcn_readfirstlane(e);

    float xv[9];
    {
        const float* xp = x + ((size_t)b * C_CH + c) * NIRR;
        #pragma unroll
        for (int i = 0; i < 9; i++) xv[i] = xp[i];
    }

    __syncthreads();

    // ---- Phase 2: contraction (flat unrolled 165-step loop) ----
    const float* T3 = lus3 + r * (NS3 * 4);
    const float* T2 = lus2 + r * (NS2 * 4);
    const float* T1 = lus1 + r * 18;

    float G3[4] = {0.f, 0.f, 0.f, 0.f};
    float G2[3] = {0.f, 0.f, 0.f};
    float G1[2] = {0.f, 0.f};

    #pragma unroll
    for (int p = 0; p < 9; p++) {
        float2 u1v = *(const float2*)(T1 + p * 2);
        G1[0] += u1v.x * xv[p];
        G1[1] += u1v.y * xv[p];
    }

    float pq = 0.f;
    #pragma unroll
    for (int s = 0; s < NS3; s++) {
        const int pi = TAB.triPair[s];
        if (s == 0 || TAB.triPair[s] != TAB.triPair[s - 1]) {
            pq = xv[TAB.pairP[pi]] * xv[TAB.pairQ[pi]];
            float4 u2v = *(const float4*)(T2 + pi * 4);
            G2[0] += u2v.x * pq;
            G2[1] += u2v.y * pq;
            G2[2] += u2v.z * pq;
        }
        float X = pq * xv[TAB.triI[s]];
        float4 u3v = *(const float4*)(T3 + s * 4);
        G3[0] += u3v.x * X;
        G3[1] += u3v.y * X;
        G3[2] += u3v.z * X;
        G3[3] += u3v.w * X;
    }

    // element weights (lane c): w3 (E,4,C), w2 (E,3,C), w1 (E,2,C)
    float acc = 0.f;
    if (r == 0) {
        #pragma unroll
        for (int k = 0; k < 4; k++) acc += w3_l0[(e * 4 + k) * 128 + c] * G3[k];
        #pragma unroll
        for (int k = 0; k < 3; k++) acc += w2_l0[(e * 3 + k) * 128 + c] * G2[k];
        #pragma unroll
        for (int k = 0; k < 2; k++) acc += w1_l0[(e * 2 + k) * 128 + c] * G1[k];
    } else {
        #pragma unroll
        for (int k = 0; k < 4; k++) acc += w3_l1[(e * 4 + k) * 128 + c] * G3[k];
        #pragma unroll
        for (int k = 0; k < 3; k++) acc += w2_l1[(e * 3 + k) * 128 + c] * G2[k];
        #pragma unroll
        for (int k = 0; k < 2; k++) acc += w1_l1[(e * 2 + k) * 128 + c] * G1[k];
    }
    fs[r][c] = acc;
    __syncthreads();

    // ---- Phase 3: o3.Linear + skip. 512 threads <-> 512 output columns ----
    //   tid < 128: col = tid (l0 block, weights lw0, fs[0])
    //   else: u = tid-128, m = u>>7, j = u&127 -> col = 128 + 3j + m,
    //         weights lw1 (coalesced in j), fs[1+m] (wave-uniform broadcast)
    int sel, j, col;
    const float* W;
    if (tid < 128) { sel = 0; j = tid; col = tid; W = lw0; }
    else {
        int u = tid - 128;
        int m = u >> 7;
        j = u & 127;
        sel = 1 + m;
        col = 128 + 3 * j + m;
        W = lw1;
    }
    sel = __builtin_amdgcn_readfirstlane(sel);

    float a = 0.f;
    #pragma unroll 8
    for (int ib = 0; ib < 32; ib++) {
        float4 f = *(const float4*)&fs[sel][4 * ib];
        int i0 = 4 * ib;
        a += f.x * W[(i0 + 0) * 128 + j];
        a += f.y * W[(i0 + 1) * 128 + j];
        a += f.z * W[(i0 + 2) * 128 + j];
        a += f.w * W[(i0 + 3) * 128 + j];
    }

    const float inv_sqrt_c = 0.08838834764831845f;  // 1/sqrt(128)
    size_t oi = (size_t)b * 512 + col;
    out[oi] = a * inv_sqrt_c + sc[oi];
}

extern "C" void kernel_launch(void* const* d_in, const int* in_sizes, int n_in,
                              void* d_out, int out_size, void* d_ws, size_t ws_size,
                              hipStream_t stream) {
    const float* x     = (const float*)d_in[0];
    const float* y     = (const float*)d_in[1];
    const float* sc    = (const float*)d_in[2];
    const float* u3_l0 = (const float*)d_in[3];
    const float* u2_l0 = (const float*)d_in[4];
    const float* u1_l0 = (const float*)d_in[5];
    const float* w3_l0 = (const float*)d_in[6];
    const float* w2_l0 = (const float*)d_in[7];
    const float* w1_l0 = (const float*)d_in[8];
    const float* u3_l1 = (const float*)d_in[9];
    const float* u2_l1 = (const float*)d_in[10];
    const float* u1_l1 = (const float*)d_in[11];
    const float* w3_l1 = (const float*)d_in[12];
    const float* w2_l1 = (const float*)d_in[13];
    const float* w1_l1 = (const float*)d_in[14];
    const float* lw0   = (const float*)d_in[15];
    const float* lw1   = (const float*)d_in[16];
    float* out = (float*)d_out;

    fused_kernel<<<N_NODES, 512, 0, stream>>>(
        x, y,
        u3_l0, u2_l0, u1_l0, u3_l1, u2_l1, u1_l1,
        w3_l0, w2_l0, w1_l0, w3_l1, w2_l1, w1_l1,
        lw0, lw1, sc, out);
}

// Round 12
// 137.782 us; speedup vs baseline: 1.3801x; 1.3801x over previous
//
#include <hip/hip_runtime.h>

// Problem constants (from reference)
#define N_NODES 2048
#define C_CH    128
#define NIRR    9
#define E_EL    10
// dslot mapping: 0 -> l0 (d=0), 1..3 -> l1 (d=0..2)

// Symmetrized coupling tables, role-major so each wave (one role r = ds)
// scalar-loads a contiguous slice:
//   us3: [r(4)][s3(165)][k(4)]   = 2640 floats
//   us2: [r(4)][s2(45)][k(3)]    =  540
//   us1: [r(4)][p(9)][k(2)]      =   72
#define NS3 165
#define NS2 45
#define US3_FLOATS (NS3 * 16)   // 2640
#define US2_FLOATS (NS2 * 12)   //  540
#define US1_FLOATS (9 * 8)      //   72

// Compile-time index tables for the flattened symmetric triple loop.
struct Tab {
    unsigned char pairP[NS2], pairQ[NS2];
    unsigned char triPair[NS3], triI[NS3];
};
constexpr Tab makeTab() {
    Tab t{};
    int s2 = 0, s3 = 0;
    for (int p = 0; p < 9; p++)
        for (int q = p; q < 9; q++) {
            t.pairP[s2] = (unsigned char)p;
            t.pairQ[s2] = (unsigned char)q;
            for (int i = q; i < 9; i++) {
                t.triPair[s3] = (unsigned char)s2;
                t.triI[s3] = (unsigned char)i;
                s3++;
            }
            s2++;
        }
    return t;
}
constexpr Tab TAB = makeTab();

// Symmetrize u3/u2/u1 over index-permutation orbits (monomial x_p x_q x_i is
// symmetric, so only sorted index tuples matter). 3252 floats total.
__global__ __launch_bounds__(256) void build_sym_kernel(
    const float* __restrict__ u3_l0, const float* __restrict__ u2_l0, const float* __restrict__ u1_l0,
    const float* __restrict__ u3_l1, const float* __restrict__ u2_l1, const float* __restrict__ u1_l1,
    float* __restrict__ us3, float* __restrict__ us2, float* __restrict__ us1)
{
    int t = blockIdx.x * 256 + threadIdx.x;
    if (t < US3_FLOATS) {
        int s = t >> 4, dk = t & 15, ds = dk >> 2, k = dk & 3;
        int pp = 0, qq = 0, ii = 0, cntr = 0;
        for (int p = 0; p < 9; p++)
            for (int q = p; q < 9; q++)
                for (int i = q; i < 9; i++) {
                    if (cntr == s) { pp = p; qq = q; ii = i; }
                    cntr++;
                }
        const float* u = (ds == 0) ? u3_l0 : (u3_l1 + (ds - 1) * 2916);
        int perm[6][3] = {{pp,qq,ii},{pp,ii,qq},{qq,pp,ii},{qq,ii,pp},{ii,pp,qq},{ii,qq,pp}};
        float acc = 0.f;
        #pragma unroll
        for (int j = 0; j < 6; j++)
            acc += u[((perm[j][0] * 9 + perm[j][1]) * 9 + perm[j][2]) * 4 + k];
        float mult = (pp == qq && qq == ii) ? 6.f : ((pp == qq || qq == ii) ? 2.f : 1.f);
        us3[ds * (NS3 * 4) + s * 4 + k] = acc / mult;
    } else if (t < US3_FLOATS + US2_FLOATS) {
        int t2 = t - US3_FLOATS;
        int s = t2 / 12, dk = t2 % 12, ds = dk / 3, k = dk % 3;
        int pp = 0, qq = 0, cntr = 0;
        for (int p = 0; p < 9; p++)
            for (int q = p; q < 9; q++) {
                if (cntr == s) { pp = p; qq = q; }
                cntr++;
            }
        const float* u = (ds == 0) ? u2_l0 : (u2_l1 + (ds - 1) * 243);
        float acc = u[(pp * 9 + qq) * 3 + k] + u[(qq * 9 + pp) * 3 + k];
        us2[ds * (NS2 * 3) + s * 3 + k] = (pp == qq) ? acc * 0.5f : acc;
    } else if (t < US3_FLOATS + US2_FLOATS + US1_FLOATS) {
        int t1 = t - US3_FLOATS - US2_FLOATS;
        int p = t1 >> 3, dk = t1 & 7, ds = dk >> 1, k = dk & 1;
        const float* u = (ds == 0) ? u1_l0 : (u1_l1 + (ds - 1) * 18);
        us1[ds * 18 + p * 2 + k] = u[p * 2 + k];
    }
}

// Fused contraction + o3.Linear + skip. One node per block.
// Block = 512 = 128 c x 4 roles; role r computes dslot r only (R8 structure,
// proven 48 us / VALUBusy ~75%). Epilogue restructured: threads 0..127 own
// 4 contiguous j-columns each -> W reads are coalesced global_load_dwordx4
// (1/4 the VMEM instructions of the R8 per-column scalar loads); remaining
// 6 waves retire at the barrier.
// NOTE: VGPR cap must stay >=128: (512,4) -> 128. R5's 64-cap spilled (14x).
__global__ __launch_bounds__(512, 4) void fused_kernel(
    const float* __restrict__ x, const float* __restrict__ y,
    const float* __restrict__ us3, const float* __restrict__ us2, const float* __restrict__ us1,
    const float* __restrict__ w3_l0, const float* __restrict__ w2_l0, const float* __restrict__ w1_l0,
    const float* __restrict__ w3_l1, const float* __restrict__ w2_l1, const float* __restrict__ w1_l1,
    const float* __restrict__ lw0, const float* __restrict__ lw1,
    const float* __restrict__ sc, float* __restrict__ out)
{
    __shared__ float fs[4][132];   // [dslot][c], stride 132 keeps float4 rows aligned
    int tid = threadIdx.x;
    int c = tid & 127;
    int r = __builtin_amdgcn_readfirstlane(tid >> 7);   // role == dslot, wave-uniform
    int b = blockIdx.x;

    int e = 0;
    #pragma unroll
    for (int k = 1; k < E_EL; k++)
        if (y[b * E_EL + k] > 0.5f) e = k;
    e = __builtin_amdgcn_readfirstlane(e);

    float xv[9];
    {
        const float* xp = x + ((size_t)b * C_CH + c) * NIRR;
        #pragma unroll
        for (int i = 0; i < 9; i++) xv[i] = xp[i];
    }

    const float* t3 = us3 + r * (NS3 * 4);
    const float* t2 = us2 + r * (NS2 * 3);
    const float* t1 = us1 + r * 18;

    float G3[4] = {0.f, 0.f, 0.f, 0.f};
    float G2[3] = {0.f, 0.f, 0.f};
    float G1[2] = {0.f, 0.f};

    #pragma unroll
    for (int p = 0; p < 9; p++) {
        G1[0] += t1[p * 2 + 0] * xv[p];
        G1[1] += t1[p * 2 + 1] * xv[p];
    }

    float pq = 0.f;
    #pragma unroll
    for (int s = 0; s < NS3; s++) {
        const int pi = TAB.triPair[s];
        if (s == 0 || TAB.triPair[s] != TAB.triPair[s - 1]) {
            pq = xv[TAB.pairP[pi]] * xv[TAB.pairQ[pi]];
            G2[0] += t2[pi * 3 + 0] * pq;
            G2[1] += t2[pi * 3 + 1] * pq;
            G2[2] += t2[pi * 3 + 2] * pq;
        }
        float X = pq * xv[TAB.triI[s]];
        G3[0] += t3[s * 4 + 0] * X;
        G3[1] += t3[s * 4 + 1] * X;
        G3[2] += t3[s * 4 + 2] * X;
        G3[3] += t3[s * 4 + 3] * X;
    }

    // element weights (lane c): w3 (E,4,C), w2 (E,3,C), w1 (E,2,C)
    float acc = 0.f;
    if (r == 0) {
        #pragma unroll
        for (int k = 0; k < 4; k++) acc += w3_l0[(e * 4 + k) * 128 + c] * G3[k];
        #pragma unroll
        for (int k = 0; k < 3; k++) acc += w2_l0[(e * 3 + k) * 128 + c] * G2[k];
        #pragma unroll
        for (int k = 0; k < 2; k++) acc += w1_l0[(e * 2 + k) * 128 + c] * G1[k];
    } else {
        #pragma unroll
        for (int k = 0; k < 4; k++) acc += w3_l1[(e * 4 + k) * 128 + c] * G3[k];
        #pragma unroll
        for (int k = 0; k < 3; k++) acc += w2_l1[(e * 3 + k) * 128 + c] * G2[k];
        #pragma unroll
        for (int k = 0; k < 2; k++) acc += w1_l1[(e * 2 + k) * 128 + c] * G1[k];
    }
    fs[r][c] = acc;
    __syncthreads();

    // ---- o3.Linear + skip: threads 0..127 only, 4 contiguous j-cols each ----
    //   t < 32:  l0 block, j0 = 4t,            W = lw0, fs[0], out cols j0..j0+3
    //   t >= 32: idx = t-32, m = idx>>5, j0 = 4*(idx&31), W = lw1, fs[1+m],
    //            out cols 128 + 3*(j0+jj) + m
    if (tid < 128) {
        int sel, m = 0, j0;
        const float4* W4;
        bool isl0 = (tid < 32);
        if (isl0) { sel = 0; j0 = 4 * tid; W4 = (const float4*)lw0; }
        else {
            int idx = tid - 32;
            m = idx >> 5;
            j0 = 4 * (idx & 31);
            sel = 1 + m;
            W4 = (const float4*)lw1;
        }
        int wbase = j0 >> 2;

        float a0 = 0.f, a1 = 0.f, a2 = 0.f, a3 = 0.f;
        #pragma unroll 4
        for (int ib = 0; ib < 32; ib++) {
            float4 f = *(const float4*)&fs[sel][4 * ib];
            float4 w0 = W4[(4 * ib + 0) * 32 + wbase];
            float4 w1 = W4[(4 * ib + 1) * 32 + wbase];
            float4 w2 = W4[(4 * ib + 2) * 32 + wbase];
            float4 w3 = W4[(4 * ib + 3) * 32 + wbase];
            a0 += f.x * w0.x + f.y * w1.x + f.z * w2.x + f.w * w3.x;
            a1 += f.x * w0.y + f.y * w1.y + f.z * w2.y + f.w * w3.y;
            a2 += f.x * w0.z + f.y * w1.z + f.z * w2.z + f.w * w3.z;
            a3 += f.x * w0.w + f.y * w1.w + f.z * w2.w + f.w * w3.w;
        }

        const float inv_sqrt_c = 0.08838834764831845f;  // 1/sqrt(128)
        if (isl0) {
            size_t o = (size_t)b * 512 + j0;
            float4 s = *(const float4*)(sc + o);
            float4 rr;
            rr.x = a0 * inv_sqrt_c + s.x;
            rr.y = a1 * inv_sqrt_c + s.y;
            rr.z = a2 * inv_sqrt_c + s.z;
            rr.w = a3 * inv_sqrt_c + s.w;
            *(float4*)(out + o) = rr;
        } else {
            float av[4] = {a0, a1, a2, a3};
            #pragma unroll
            for (int jj = 0; jj < 4; jj++) {
                size_t o = (size_t)b * 512 + 128 + 3 * (j0 + jj) + m;
                out[o] = av[jj] * inv_sqrt_c + sc[o];
            }
        }
    }
}

extern "C" void kernel_launch(void* const* d_in, const int* in_sizes, int n_in,
                              void* d_out, int out_size, void* d_ws, size_t ws_size,
                              hipStream_t stream) {
    const float* x     = (const float*)d_in[0];
    const float* y     = (const float*)d_in[1];
    const float* sc    = (const float*)d_in[2];
    const float* u3_l0 = (const float*)d_in[3];
    const float* u2_l0 = (const float*)d_in[4];
    const float* u1_l0 = (const float*)d_in[5];
    const float* w3_l0 = (const float*)d_in[6];
    const float* w2_l0 = (const float*)d_in[7];
    const float* w1_l0 = (const float*)d_in[8];
    const float* u3_l1 = (const float*)d_in[9];
    const float* u2_l1 = (const float*)d_in[10];
    const float* u1_l1 = (const float*)d_in[11];
    const float* w3_l1 = (const float*)d_in[12];
    const float* w2_l1 = (const float*)d_in[13];
    const float* w1_l1 = (const float*)d_in[14];
    const float* lw0   = (const float*)d_in[15];
    const float* lw1   = (const float*)d_in[16];
    float* out = (float*)d_out;

    // Workspace layout (floats): us3 | us2 | us1
    float* us3 = (float*)d_ws;
    float* us2 = us3 + US3_FLOATS;
    float* us1 = us2 + US2_FLOATS;

    build_sym_kernel<<<13, 256, 0, stream>>>(
        u3_l0, u2_l0, u1_l0, u3_l1, u2_l1, u1_l1, us3, us2, us1);
    fused_kernel<<<N_NODES, 512, 0, stream>>>(
        x, y, us3, us2, us1,
        w3_l0, w2_l0, w1_l0, w3_l1, w2_l1, w1_l1,
        lw0, lw1, sc, out);
}

// Round 13
// 132.881 us; speedup vs baseline: 1.4310x; 1.0369x over previous
//
#include <hip/hip_runtime.h>

// Problem constants (from reference)
#define N_NODES 2048
#define C_CH    128
#define NIRR    9
#define E_EL    10
// dslot mapping: 0 -> l0 (d=0), 1..3 -> l1 (d=0..2)

// Symmetrized coupling tables, role-major so each wave (one role r = ds)
// scalar-loads a contiguous 8B-aligned slice:
//   us3: [r(4)][s3(165)][k(4)]      = 2640 floats (role stride 660 = 2640B, 8B-aligned)
//   us2: [r(4)][s2(45)][k(4 pad)]   =  720 floats (role stride 180 = 720B, 8B-aligned; k=3 zero)
//   us1: [r(4)][p(9)][k(2)]         =   72 floats (role stride 18 = 72B, 8B-aligned)
#define NS3 165
#define NS2 45
#define US3_FLOATS (NS3 * 16)       // 2640
#define US2_FLOATS (NS2 * 16)       //  720 (padded)
#define US1_FLOATS (9 * 8)          //   72

typedef float pf2 __attribute__((ext_vector_type(2)));

// Compile-time index tables for the flattened symmetric triple loop.
struct Tab {
    unsigned char pairP[NS2], pairQ[NS2];
    unsigned char triPair[NS3], triI[NS3];
};
constexpr Tab makeTab() {
    Tab t{};
    int s2 = 0, s3 = 0;
    for (int p = 0; p < 9; p++)
        for (int q = p; q < 9; q++) {
            t.pairP[s2] = (unsigned char)p;
            t.pairQ[s2] = (unsigned char)q;
            for (int i = q; i < 9; i++) {
                t.triPair[s3] = (unsigned char)s2;
                t.triI[s3] = (unsigned char)i;
                s3++;
            }
            s2++;
        }
    return t;
}
constexpr Tab TAB = makeTab();

// Symmetrize u3/u2/u1 over index-permutation orbits (monomial x_p x_q x_i is
// symmetric, so only sorted index tuples matter).
__global__ __launch_bounds__(256) void build_sym_kernel(
    const float* __restrict__ u3_l0, const float* __restrict__ u2_l0, const float* __restrict__ u1_l0,
    const float* __restrict__ u3_l1, const float* __restrict__ u2_l1, const float* __restrict__ u1_l1,
    float* __restrict__ us3, float* __restrict__ us2, float* __restrict__ us1)
{
    int t = blockIdx.x * 256 + threadIdx.x;
    if (t < US3_FLOATS) {
        int k = t & 3;
        int rs = t >> 2;
        int s = rs % NS3;
        int ds = rs / NS3;
        int pp = 0, qq = 0, ii = 0, cntr = 0;
        for (int p = 0; p < 9; p++)
            for (int q = p; q < 9; q++)
                for (int i = q; i < 9; i++) {
                    if (cntr == s) { pp = p; qq = q; ii = i; }
                    cntr++;
                }
        const float* u = (ds == 0) ? u3_l0 : (u3_l1 + (ds - 1) * 2916);
        int perm[6][3] = {{pp,qq,ii},{pp,ii,qq},{qq,pp,ii},{qq,ii,pp},{ii,pp,qq},{ii,qq,pp}};
        float acc = 0.f;
        #pragma unroll
        for (int j = 0; j < 6; j++)
            acc += u[((perm[j][0] * 9 + perm[j][1]) * 9 + perm[j][2]) * 4 + k];
        float mult = (pp == qq && qq == ii) ? 6.f : ((pp == qq || qq == ii) ? 2.f : 1.f);
        us3[ds * (NS3 * 4) + s * 4 + k] = acc / mult;
    } else if (t < US3_FLOATS + US2_FLOATS) {
        int t2 = t - US3_FLOATS;
        int k = t2 & 3;
        int rs = t2 >> 2;
        int s = rs % NS2;
        int ds = rs / NS2;
        float v = 0.f;
        if (k < 3) {
            int pp = 0, qq = 0, cntr = 0;
            for (int p = 0; p < 9; p++)
                for (int q = p; q < 9; q++) {
                    if (cntr == s) { pp = p; qq = q; }
                    cntr++;
                }
            const float* u = (ds == 0) ? u2_l0 : (u2_l1 + (ds - 1) * 243);
            float acc = u[(pp * 9 + qq) * 3 + k] + u[(qq * 9 + pp) * 3 + k];
            v = (pp == qq) ? acc * 0.5f : acc;
        }
        us2[ds * (NS2 * 4) + s * 4 + k] = v;
    } else if (t < US3_FLOATS + US2_FLOATS + US1_FLOATS) {
        int t1 = t - US3_FLOATS - US2_FLOATS;
        int p = t1 >> 3, dk = t1 & 7, ds = dk >> 1, k = dk & 1;
        const float* u = (ds == 0) ? u1_l0 : (u1_l1 + (ds - 1) * 18);
        us1[ds * 18 + p * 2 + k] = u[p * 2 + k];
    }
}

// Fused contraction + o3.Linear + skip. One node per block.
// Block = 512 = 128 c x 4 roles; role r computes dslot r only (R8 structure).
// Accumulation uses packed 2xfp32 (v_pk_fma_f32) - the only path to the
// 157 TF fp32 vector peak; plain v_fmac caps at half rate.
// NOTE: VGPR cap must stay >=128: (512,4) -> 128. R5's 64-cap spilled (14x).
__global__ __launch_bounds__(512, 4) void fused_kernel(
    const float* __restrict__ x, const float* __restrict__ y,
    const float* __restrict__ us3, const float* __restrict__ us2, const float* __restrict__ us1,
    const float* __restrict__ w3_l0, const float* __restrict__ w2_l0, const float* __restrict__ w1_l0,
    const float* __restrict__ w3_l1, const float* __restrict__ w2_l1, const float* __restrict__ w1_l1,
    const float* __restrict__ lw0, const float* __restrict__ lw1,
    const float* __restrict__ sc, float* __restrict__ out)
{
    __shared__ float fs[4][132];   // [dslot][c]
    int tid = threadIdx.x;
    int c = tid & 127;
    int r = __builtin_amdgcn_readfirstlane(tid >> 7);   // role == dslot, wave-uniform
    int b = blockIdx.x;

    int e = 0;
    #pragma unroll
    for (int k = 1; k < E_EL; k++)
        if (y[b * E_EL + k] > 0.5f) e = k;
    e = __builtin_amdgcn_readfirstlane(e);

    float xv[9];
    {
        const float* xp = x + ((size_t)b * C_CH + c) * NIRR;
        #pragma unroll
        for (int i = 0; i < 9; i++) xv[i] = xp[i];
    }

    const float* t3 = us3 + r * (NS3 * 4);
    const float* t2 = us2 + r * (NS2 * 4);
    const float* t1 = us1 + r * 18;
    const pf2* T3v = (const pf2*)t3;   // pairs (k0,k1),(k2,k3) per s
    const pf2* T2v = (const pf2*)t2;   // pair (k0,k1) at 2s; k2 at t2[4s+2]
    const pf2* T1v = (const pf2*)t1;   // pair (k0,k1) per p

    pf2 G3a = {0.f, 0.f}, G3b = {0.f, 0.f};
    pf2 G2a = {0.f, 0.f};
    float G2c = 0.f;
    pf2 G1v = {0.f, 0.f};

    #pragma unroll
    for (int p = 0; p < 9; p++) {
        pf2 xpv = {xv[p], xv[p]};
        G1v = __builtin_elementwise_fma(T1v[p], xpv, G1v);
    }

    float pq = 0.f;
    #pragma unroll
    for (int s = 0; s < NS3; s++) {
        const int pi = TAB.triPair[s];
        if (s == 0 || TAB.triPair[s] != TAB.triPair[s - 1]) {
            pq = xv[TAB.pairP[pi]] * xv[TAB.pairQ[pi]];
            pf2 pqv = {pq, pq};
            G2a = __builtin_elementwise_fma(T2v[pi * 2], pqv, G2a);
            G2c = __builtin_fmaf(t2[pi * 4 + 2], pq, G2c);
        }
        float X = pq * xv[TAB.triI[s]];
        pf2 Xv = {X, X};
        G3a = __builtin_elementwise_fma(T3v[s * 2], Xv, G3a);
        G3b = __builtin_elementwise_fma(T3v[s * 2 + 1], Xv, G3b);
    }

    float G3[4] = {G3a.x, G3a.y, G3b.x, G3b.y};
    float G2[3] = {G2a.x, G2a.y, G2c};
    float G1[2] = {G1v.x, G1v.y};

    // element weights (lane c): w3 (E,4,C), w2 (E,3,C), w1 (E,2,C)
    float acc = 0.f;
    if (r == 0) {
        #pragma unroll
        for (int k = 0; k < 4; k++) acc += w3_l0[(e * 4 + k) * 128 + c] * G3[k];
        #pragma unroll
        for (int k = 0; k < 3; k++) acc += w2_l0[(e * 3 + k) * 128 + c] * G2[k];
        #pragma unroll
        for (int k = 0; k < 2; k++) acc += w1_l0[(e * 2 + k) * 128 + c] * G1[k];
    } else {
        #pragma unroll
        for (int k = 0; k < 4; k++) acc += w3_l1[(e * 4 + k) * 128 + c] * G3[k];
        #pragma unroll
        for (int k = 0; k < 3; k++) acc += w2_l1[(e * 3 + k) * 128 + c] * G2[k];
        #pragma unroll
        for (int k = 0; k < 2; k++) acc += w1_l1[(e * 2 + k) * 128 + c] * G1[k];
    }
    fs[r][c] = acc;
    __syncthreads();

    // ---- o3.Linear + skip: threads 0..127 only, 4 contiguous j-cols each ----
    if (tid < 128) {
        int sel, m = 0, j0;
        const float4* W4;
        bool isl0 = (tid < 32);
        if (isl0) { sel = 0; j0 = 4 * tid; W4 = (const float4*)lw0; }
        else {
            int idx = tid - 32;
            m = idx >> 5;
            j0 = 4 * (idx & 31);
            sel = 1 + m;
            W4 = (const float4*)lw1;
        }
        int wbase = j0 >> 2;

        float a0 = 0.f, a1 = 0.f, a2 = 0.f, a3 = 0.f;
        #pragma unroll 4
        for (int ib = 0; ib < 32; ib++) {
            float4 f = *(const float4*)&fs[sel][4 * ib];
            float4 w0 = W4[(4 * ib + 0) * 32 + wbase];
            float4 w1 = W4[(4 * ib + 1) * 32 + wbase];
            float4 w2 = W4[(4 * ib + 2) * 32 + wbase];
            float4 w3 = W4[(4 * ib + 3) * 32 + wbase];
            a0 += f.x * w0.x + f.y * w1.x + f.z * w2.x + f.w * w3.x;
            a1 += f.x * w0.y + f.y * w1.y + f.z * w2.y + f.w * w3.y;
            a2 += f.x * w0.z + f.y * w1.z + f.z * w2.z + f.w * w3.z;
            a3 += f.x * w0.w + f.y * w1.w + f.z * w2.w + f.w * w3.w;
        }

        const float inv_sqrt_c = 0.08838834764831845f;  // 1/sqrt(128)
        if (isl0) {
            size_t o = (size_t)b * 512 + j0;
            float4 s = *(const float4*)(sc + o);
            float4 rr;
            rr.x = a0 * inv_sqrt_c + s.x;
            rr.y = a1 * inv_sqrt_c + s.y;
            rr.z = a2 * inv_sqrt_c + s.z;
            rr.w = a3 * inv_sqrt_c + s.w;
            *(float4*)(out + o) = rr;
        } else {
            float av[4] = {a0, a1, a2, a3};
            #pragma unroll
            for (int jj = 0; jj < 4; jj++) {
                size_t o = (size_t)b * 512 + 128 + 3 * (j0 + jj) + m;
                out[o] = av[jj] * inv_sqrt_c + sc[o];
            }
        }
    }
}

extern "C" void kernel_launch(void* const* d_in, const int* in_sizes, int n_in,
                              void* d_out, int out_size, void* d_ws, size_t ws_size,
                              hipStream_t stream) {
    const float* x     = (const float*)d_in[0];
    const float* y     = (const float*)d_in[1];
    const float* sc    = (const float*)d_in[2];
    const float* u3_l0 = (const float*)d_in[3];
    const float* u2_l0 = (const float*)d_in[4];
    const float* u1_l0 = (const float*)d_in[5];
    const float* w3_l0 = (const float*)d_in[6];
    const float* w2_l0 = (const float*)d_in[7];
    const float* w1_l0 = (const float*)d_in[8];
    const float* u3_l1 = (const float*)d_in[9];
    const float* u2_l1 = (const float*)d_in[10];
    const float* u1_l1 = (const float*)d_in[11];
    const float* w3_l1 = (const float*)d_in[12];
    const float* w2_l1 = (const float*)d_in[13];
    const float* w1_l1 = (const float*)d_in[14];
    const float* lw0   = (const float*)d_in[15];
    const float* lw1   = (const float*)d_in[16];
    float* out = (float*)d_out;

    // Workspace layout (floats): us3 | us2 | us1
    float* us3 = (float*)d_ws;
    float* us2 = us3 + US3_FLOATS;
    float* us1 = us2 + US2_FLOATS;

    int tot = US3_FLOATS + US2_FLOATS + US1_FLOATS;
    build_sym_kernel<<<(tot + 255) / 256, 256, 0, stream>>>(
        u3_l0, u2_l0, u1_l0, u3_l1, u2_l1, u1_l1, us3, us2, us1);
    fused_kernel<<<N_NODES, 512, 0, stream>>>(
        x, y, us3, us2, us1,
        w3_l0, w2_l0, w1_l0, w3_l1, w2_l1, w1_l1,
        lw0, lw1, sc, out);
}